// Round 6
// baseline (191.653 us; speedup 1.0000x reference)
//
#include <hip/hip_runtime.h>

// Spatial transformer: trilinear warp of src by flow, border padding.
// D=160, H=192, W=160.  u = (idx + flow) * S/(S-1) - 0.5, clamp, trilinear.
// grid input (identity meshgrid) recomputed from thread index.
//
// R5 lesson: scattered demand-miss concurrency x latency is the wall
// (~24k line-touches/CU at ~400cyc with ~80 outstanding). This round:
// per-tile LDS staging. Prepass packs src to bf16 (9.8MB, L2-resident
// slabs). Each block: stage 23x23x48 bf16 window (halo 7) with coalesced
// reads -> gather 8 corners per voxel from LDS. ~2% out-of-window voxels
// fall back to direct f32 gathers (proven R2 path).

#define DD 160
#define HH 192
#define WW 160
#define DHW (DD * HH * WW)

#define TZ 8
#define TY 8
#define TX 32
#define HZ 7
#define WIN_Z 23               /* TZ + 2*HZ + 1 */
#define WIN_Y 23
#define WIN_X 48               /* TX + 16 (xlo = bx-8) */
#define NROWS (WIN_Z * WIN_Y)  /* 529 */
#define NCHUNKS (NROWS * (WIN_X / 4)) /* 6348 uint2 chunks */

#define NTZ (DD / TZ)          /* 20 */
#define NTY (HH / TY)          /* 24 */
#define NTX (WW / TX)          /* 5  */
#define NTILES (NTZ * NTY * NTX) /* 2400 */

#define VB_BYTES ((size_t)DHW * 2)

__device__ __forceinline__ unsigned short bf16_rn(float f) {
    unsigned int u = __float_as_uint(f);
    return (unsigned short)((u + 0x7FFFu + ((u >> 16) & 1u)) >> 16);
}
__device__ __forceinline__ float bf2f(unsigned short s) {
    return __uint_as_float(((unsigned int)s) << 16);
}

// ---------------- prepass: src f32 -> bf16 volume ----------------
__global__ __launch_bounds__(256) void pack_bf16_kernel(
    const float* __restrict__ src, unsigned short* __restrict__ vb)
{
    int t = blockIdx.x * 256 + (int)threadIdx.x;  // 614,400 threads, 8 elems each
    int base = t * 8;
    float4 a = *(const float4*)(src + base);
    float4 b = *(const float4*)(src + base + 4);
    uint4 o;
    o.x = (unsigned int)bf16_rn(a.x) | ((unsigned int)bf16_rn(a.y) << 16);
    o.y = (unsigned int)bf16_rn(a.z) | ((unsigned int)bf16_rn(a.w) << 16);
    o.z = (unsigned int)bf16_rn(b.x) | ((unsigned int)bf16_rn(b.y) << 16);
    o.w = (unsigned int)bf16_rn(b.z) | ((unsigned int)bf16_rn(b.w) << 16);
    *(uint4*)(vb + base) = o;
}

// ---------------- main: LDS-staged trilinear warp ----------------
struct __align__(4) F2 { float a, b; };

__global__ __launch_bounds__(256) void warp_lds_kernel(
    const unsigned short* __restrict__ vb,
    const float* __restrict__ src,
    const float* __restrict__ flow,
    float* __restrict__ out)
{
    // XCD swizzle: XCD k gets tiles [300k, 300k+300) = contiguous z-slab
    // -> its vb slab (~1.3 MB) stays resident in that XCD's L2.
    int b = blockIdx.x;
    int nb = (b & 7) * 300 + (b >> 3);
    int tzt = nb / (NTY * NTX);
    int rem = nb - tzt * (NTY * NTX);
    int tyt = rem / NTX;
    int txt = rem - tyt * NTX;
    int bz = tzt * TZ, by = tyt * TY, bx = txt * TX;
    int zlo = bz - HZ, ylo = by - HZ, xlo = bx - 8;

    __shared__ unsigned short sbuf[WIN_Z * WIN_Y * WIN_X];  // 50,784 B

    // ---- stage window (coalesced uint2 chunks, clamped at borders) ----
    for (int c = (int)threadIdx.x; c < NCHUNKS; c += 256) {
        int r = c / 12;
        int i = c - r * 12;
        int wz = r / WIN_Y;
        int wy = r - wz * WIN_Y;
        int gz = min(max(zlo + wz, 0), DD - 1);
        int gy = min(max(ylo + wy, 0), HH - 1);
        int gx0 = xlo + i * 4;
        const unsigned short* rowp = vb + ((size_t)gz * HH + gy) * WW;
        unsigned int u0, u1;
        if (gx0 >= 0 && gx0 + 3 <= WW - 1) {
            uint2 q = *(const uint2*)(rowp + gx0);   // 8B aligned (gx0 % 4 == 0)
            u0 = q.x; u1 = q.y;
        } else {
            unsigned int e0 = rowp[min(max(gx0,     0), WW - 1)];
            unsigned int e1 = rowp[min(max(gx0 + 1, 0), WW - 1)];
            unsigned int e2 = rowp[min(max(gx0 + 2, 0), WW - 1)];
            unsigned int e3 = rowp[min(max(gx0 + 3, 0), WW - 1)];
            u0 = e0 | (e1 << 16); u1 = e2 | (e3 << 16);
        }
        *(uint2*)(&sbuf[(wz * WIN_Y + wy) * WIN_X + i * 4]) = make_uint2(u0, u1);
    }
    __syncthreads();

    const float SX = (float)WW / (float)(WW - 1);
    const float SY = (float)HH / (float)(HH - 1);
    const float SZ = (float)DD / (float)(DD - 1);

    // ---- 2 float4-groups per thread: 2048 voxels/block ----
    #pragma unroll
    for (int g2 = 0; g2 < 2; ++g2) {
        int g = (int)threadIdx.x + g2 * 256;   // 0..511
        int row = g >> 3;                      // 0..63 : (tz,ty) in tile
        int col = g & 7;                       // float4 slot in x
        int tzv = row >> 3, tyv = row & 7;
        int gz = bz + tzv, gy = by + tyv, gx = bx + col * 4;
        int idx = (gz * HH + gy) * WW + gx;

        float4 f0  = *(const float4*)(flow + idx);            // -> D/z
        float4 f1  = *(const float4*)(flow + DHW + idx);      // -> H/y
        float4 f2v = *(const float4*)(flow + 2 * DHW + idx);  // -> W/x
        const float* f0p = (const float*)&f0;
        const float* f1p = (const float*)&f1;
        const float* f2p = (const float*)&f2v;

        float res[4];
        #pragma unroll
        for (int v = 0; v < 4; ++v) {
            float ux = fmaf((float)(gx + v) + f2p[v], SX, -0.5f);
            float uy = fmaf((float)gy + f1p[v],       SY, -0.5f);
            float uz = fmaf((float)gz + f0p[v],       SZ, -0.5f);
            ux = fminf(fmaxf(ux, 0.0f), (float)(WW - 1));
            uy = fminf(fmaxf(uy, 0.0f), (float)(HH - 1));
            uz = fminf(fmaxf(uz, 0.0f), (float)(DD - 1));
            float x0f = floorf(ux), y0f = floorf(uy), z0f = floorf(uz);
            float fx = ux - x0f, fy = uy - y0f, fz = uz - z0f;
            int x0 = (int)x0f, y0 = (int)y0f, z0 = (int)z0f;
            int x1 = min(x0 + 1, WW - 1);
            int y1 = min(y0 + 1, HH - 1);
            int z1 = min(z0 + 1, DD - 1);

            int lz0 = z0 - zlo, lz1 = z1 - zlo;
            int ly0 = y0 - ylo, ly1 = y1 - ylo;
            int lx0 = x0 - xlo, lx1 = x1 - xlo;
            bool in = (lz0 >= 0) & (lz1 <= WIN_Z - 1) &
                      (ly0 >= 0) & (ly1 <= WIN_Y - 1) &
                      (lx0 >= 0) & (lx1 <= WIN_X - 1);

            float c000, c001, c010, c011, c100, c101, c110, c111;
            if (in) {
                int b00 = (lz0 * WIN_Y + ly0) * WIN_X;
                int b01 = (lz0 * WIN_Y + ly1) * WIN_X;
                int b10 = (lz1 * WIN_Y + ly0) * WIN_X;
                int b11 = (lz1 * WIN_Y + ly1) * WIN_X;
                c000 = bf2f(sbuf[b00 + lx0]); c001 = bf2f(sbuf[b00 + lx1]);
                c010 = bf2f(sbuf[b01 + lx0]); c011 = bf2f(sbuf[b01 + lx1]);
                c100 = bf2f(sbuf[b10 + lx0]); c101 = bf2f(sbuf[b10 + lx1]);
                c110 = bf2f(sbuf[b11 + lx0]); c111 = bf2f(sbuf[b11 + lx1]);
            } else {
                // rare (~2%): direct f32 gathers (proven R2 path)
                int xb = min(x0, WW - 2);
                bool xe = (x0 == WW - 1);
                F2 q00 = *(const F2*)(src + ((size_t)z0 * HH + y0) * WW + xb);
                F2 q01 = *(const F2*)(src + ((size_t)z0 * HH + y1) * WW + xb);
                F2 q10 = *(const F2*)(src + ((size_t)z1 * HH + y0) * WW + xb);
                F2 q11 = *(const F2*)(src + ((size_t)z1 * HH + y1) * WW + xb);
                c000 = xe ? q00.b : q00.a; c001 = q00.b;
                c010 = xe ? q01.b : q01.a; c011 = q01.b;
                c100 = xe ? q10.b : q10.a; c101 = q10.b;
                c110 = xe ? q11.b : q11.a; c111 = q11.b;
            }
            float r00 = fmaf(fx, c001 - c000, c000);
            float r01 = fmaf(fx, c011 - c010, c010);
            float r10 = fmaf(fx, c101 - c100, c100);
            float r11 = fmaf(fx, c111 - c110, c110);
            float r0  = fmaf(fy, r01 - r00, r00);
            float r1  = fmaf(fy, r11 - r10, r10);
            res[v]    = fmaf(fz, r1 - r0, r0);
        }
        *(float4*)(out + idx) = make_float4(res[0], res[1], res[2], res[3]);
    }
}

// ---------------- fallback (proven R2 kernel) if ws too small ----------------
__global__ __launch_bounds__(256) void warp_direct_kernel(
    const float* __restrict__ src,
    const float* __restrict__ flow,
    float* __restrict__ out)
{
    int b = blockIdx.x;
    int nb = (b & 7) * 600 + (b >> 3);
    int base = (nb * 256 + (int)threadIdx.x) * 4;

    int w = base % WW;
    int tmp = base / WW;
    int h = tmp % HH;
    int d = tmp / HH;

    const float4 f0  = *(const float4*)(flow + base);
    const float4 f1  = *(const float4*)(flow + DHW + base);
    const float4 f2v = *(const float4*)(flow + 2 * DHW + base);
    const float* f0p = (const float*)&f0;
    const float* f1p = (const float*)&f1;
    const float* f2p = (const float*)&f2v;

    const float SX = (float)WW / (float)(WW - 1);
    const float SY = (float)HH / (float)(HH - 1);
    const float SZ = (float)DD / (float)(DD - 1);

    float res[4];
    #pragma unroll
    for (int v = 0; v < 4; ++v) {
        float ux = fmaf((float)(w + v) + f2p[v], SX, -0.5f);
        float uy = fmaf((float)h + f1p[v],       SY, -0.5f);
        float uz = fmaf((float)d + f0p[v],       SZ, -0.5f);
        ux = fminf(fmaxf(ux, 0.0f), (float)(WW - 1));
        uy = fminf(fmaxf(uy, 0.0f), (float)(HH - 1));
        uz = fminf(fmaxf(uz, 0.0f), (float)(DD - 1));
        float x0f = floorf(ux), y0f = floorf(uy), z0f = floorf(uz);
        float fx = ux - x0f, fy = uy - y0f, fz = uz - z0f;
        int x0 = (int)x0f, y0 = (int)y0f, z0 = (int)z0f;
        int y1 = min(y0 + 1, HH - 1);
        int z1 = min(z0 + 1, DD - 1);
        int xb = min(x0, WW - 2);
        bool xe = (x0 == WW - 1);
        F2 q00 = *(const F2*)(src + ((size_t)z0 * HH + y0) * WW + xb);
        F2 q01 = *(const F2*)(src + ((size_t)z0 * HH + y1) * WW + xb);
        F2 q10 = *(const F2*)(src + ((size_t)z1 * HH + y0) * WW + xb);
        F2 q11 = *(const F2*)(src + ((size_t)z1 * HH + y1) * WW + xb);
        float c000 = xe ? q00.b : q00.a, c001 = q00.b;
        float c010 = xe ? q01.b : q01.a, c011 = q01.b;
        float c100 = xe ? q10.b : q10.a, c101 = q10.b;
        float c110 = xe ? q11.b : q11.a, c111 = q11.b;
        float r00 = fmaf(fx, c001 - c000, c000);
        float r01 = fmaf(fx, c011 - c010, c010);
        float r10 = fmaf(fx, c101 - c100, c100);
        float r11 = fmaf(fx, c111 - c110, c110);
        float r0  = fmaf(fy, r01 - r00, r00);
        float r1  = fmaf(fy, r11 - r10, r10);
        res[v]    = fmaf(fz, r1 - r0, r0);
    }
    *(float4*)(out + base) = make_float4(res[0], res[1], res[2], res[3]);
}

extern "C" void kernel_launch(void* const* d_in, const int* in_sizes, int n_in,
                              void* d_out, int out_size, void* d_ws, size_t ws_size,
                              hipStream_t stream) {
    const float* src  = (const float*)d_in[0];   // [1,1,D,H,W]
    const float* flow = (const float*)d_in[1];   // [1,3,D,H,W]
    // d_in[2] identity grid: unused (recomputed)
    float* out = (float*)d_out;

    if (ws_size >= VB_BYTES) {
        unsigned short* vb = (unsigned short*)d_ws;
        pack_bf16_kernel<<<DHW / 8 / 256, 256, 0, stream>>>(src, vb);
        warp_lds_kernel<<<NTILES, 256, 0, stream>>>(vb, src, flow, out);
    } else {
        warp_direct_kernel<<<DHW / 4 / 256, 256, 0, stream>>>(src, flow, out);
    }
}

// Round 7
// 190.784 us; speedup vs baseline: 1.0046x; 1.0046x over previous
//
#include <hip/hip_runtime.h>

// Spatial transformer: trilinear warp of src by flow, border padding.
// D=160, H=192, W=160.  u = (idx + flow) * S/(S-1) - 0.5, clamp, trilinear.
// grid input (identity meshgrid) recomputed from thread index.
//
// R5 structure (4-parity bf16 stencil table, 1x16B-equivalent fetch/voxel)
// + R7 change: 8 voxels/thread, 16 gather loads forced in-flight via
// volatile inline asm (compiler provably re-serializes them otherwise:
// VGPR stayed 24-36 across R2-R5). Manual s_waitcnt ties all results.

#define DD 160
#define HH 192
#define WW 160
#define DHW (DD * HH * WW)
#define ZP (DD / 2)   /* 80 */
#define YP (HH / 2)   /* 96 */
#define COPY_ENTRIES (ZP * YP * WW)            /* 1,228,800 entries x 8B */
#define WS_NEEDED (4ULL * COPY_ENTRIES * 8ULL) /* 39,321,600 B */

__device__ __forceinline__ unsigned short bf16_rn(float f) {
    unsigned int u = __float_as_uint(f);
    return (unsigned short)((u + 0x7FFFu + ((u >> 16) & 1u)) >> 16);
}

// ---------------- prepass: build 4 parity-packed bf16 stencil copies ----------------
// copy(cz,cy) entry [zp][yp][x] (2 uints):
//   u0 = bf(z0,y0,x) | bf(z1,y0,x)<<16
//   u1 = bf(z0,y1,x) | bf(z1,y1,x)<<16
// where z0=2*zp+cz, z1=min(z0+1,DD-1), y0=2*yp+cy, y1=min(y0+1,HH-1).
__global__ __launch_bounds__(256) void pack_kernel(
    const float* __restrict__ src, unsigned int* __restrict__ tab)
{
    int t = blockIdx.x * 256 + (int)threadIdx.x;   // 307,200 threads
    int xq  = t % (WW / 4);
    int rem = t / (WW / 4);
    int yp  = rem % YP;
    int zp  = rem / YP;                             // [0,80)
    int x = xq * 4;

    int zs[3] = { 2 * zp, 2 * zp + 1, min(2 * zp + 2, DD - 1) };
    int ys[3] = { 2 * yp, 2 * yp + 1, min(2 * yp + 2, HH - 1) };

    float4 r[3][3];
    #pragma unroll
    for (int i = 0; i < 3; ++i)
        #pragma unroll
        for (int j = 0; j < 3; ++j)
            r[i][j] = *(const float4*)(src + ((size_t)zs[i] * HH + ys[j]) * WW + x);

    #pragma unroll
    for (int cz = 0; cz < 2; ++cz)
        #pragma unroll
        for (int cy = 0; cy < 2; ++cy) {
            unsigned int e[8];
            #pragma unroll
            for (int k = 0; k < 4; ++k) {
                float a = ((const float*)&r[cz    ][cy    ])[k];
                float b = ((const float*)&r[cz + 1][cy    ])[k];
                float c = ((const float*)&r[cz    ][cy + 1])[k];
                float d = ((const float*)&r[cz + 1][cy + 1])[k];
                e[2 * k]     = (unsigned int)bf16_rn(a) | ((unsigned int)bf16_rn(b) << 16);
                e[2 * k + 1] = (unsigned int)bf16_rn(c) | ((unsigned int)bf16_rn(d) << 16);
            }
            unsigned int* dst = tab +
                ((size_t)(cz * 2 + cy) * COPY_ENTRIES + ((size_t)zp * YP + yp) * WW + x) * 2;
            *(uint4*)(dst)     = make_uint4(e[0], e[1], e[2], e[3]);
            *(uint4*)(dst + 4) = make_uint4(e[4], e[5], e[6], e[7]);
        }
}

// ---------------- main: 8 voxels/thread, forced 16-deep gather MLP ----------------
__global__ __launch_bounds__(256) void warp_kernel(
    const unsigned int* __restrict__ tab,
    const float* __restrict__ flow,
    float* __restrict__ out)
{
    // XCD swizzle: XCD k gets contiguous blocks [300k,300k+300) -> its slab
    // of the table stays hot in L2.
    int b = blockIdx.x;
    int nb = (b & 7) * 300 + (b >> 3);
    int base = (nb * 256 + (int)threadIdx.x) * 8;

    int w = base % WW;                 // 8 | 160 -> all 8 voxels same (d,h)
    int tmp = base / WW;
    int h = tmp % HH;
    int d = tmp / HH;

    const float4 f0a = *(const float4*)(flow + base);
    const float4 f0b = *(const float4*)(flow + base + 4);
    const float4 f1a = *(const float4*)(flow + DHW + base);
    const float4 f1b = *(const float4*)(flow + DHW + base + 4);
    const float4 f2a = *(const float4*)(flow + 2 * DHW + base);
    const float4 f2b = *(const float4*)(flow + 2 * DHW + base + 4);

    float fl0[8] = { f0a.x, f0a.y, f0a.z, f0a.w, f0b.x, f0b.y, f0b.z, f0b.w };
    float fl1[8] = { f1a.x, f1a.y, f1a.z, f1a.w, f1b.x, f1b.y, f1b.z, f1b.w };
    float fl2[8] = { f2a.x, f2a.y, f2a.z, f2a.w, f2b.x, f2b.y, f2b.z, f2b.w };

    const float SX = (float)WW / (float)(WW - 1);
    const float SY = (float)HH / (float)(HH - 1);
    const float SZ = (float)DD / (float)(DD - 1);

    float fx[8], fy[8], fz[8];
    bool  xe[8];
    const unsigned long long* pp[8];

    // ---- phase 1: addresses & weights ----
    #pragma unroll
    for (int v = 0; v < 8; ++v) {
        float ux = fmaf((float)(w + v) + fl2[v], SX, -0.5f);
        float uy = fmaf((float)h + fl1[v],       SY, -0.5f);
        float uz = fmaf((float)d + fl0[v],       SZ, -0.5f);
        ux = fminf(fmaxf(ux, 0.0f), (float)(WW - 1));
        uy = fminf(fmaxf(uy, 0.0f), (float)(HH - 1));
        uz = fminf(fmaxf(uz, 0.0f), (float)(DD - 1));
        float x0f = floorf(ux), y0f = floorf(uy), z0f = floorf(uz);
        fx[v] = ux - x0f; fy[v] = uy - y0f; fz[v] = uz - z0f;
        int x0 = (int)x0f, y0 = (int)y0f, z0 = (int)z0f;
        int zp = z0 >> 1, cz = z0 & 1;
        int yp = y0 >> 1, cy = y0 & 1;
        int xb = min(x0, WW - 2);
        xe[v] = (x0 == WW - 1);
        pp[v] = (const unsigned long long*)(tab +
            ((size_t)((cz << 1) | cy) * COPY_ENTRIES + ((size_t)zp * YP + yp) * WW + xb) * 2);
    }

    // ---- phase 2: 16 gather loads, order pinned by volatile asm ----
    unsigned long long qlo[8], qhi[8];
    #pragma unroll
    for (int v = 0; v < 8; ++v)
        asm volatile("global_load_dwordx2 %0, %1, off"
                     : "=v"(qlo[v]) : "v"(pp[v]));
    #pragma unroll
    for (int v = 0; v < 8; ++v)
        asm volatile("global_load_dwordx2 %0, %1, off offset:8"
                     : "=v"(qhi[v]) : "v"(pp[v]));
    // Manual drain; results tied as "+v" so no consumer schedules above it.
    asm volatile("s_waitcnt vmcnt(0)"
                 : "+v"(qlo[0]), "+v"(qlo[1]), "+v"(qlo[2]), "+v"(qlo[3]),
                   "+v"(qlo[4]), "+v"(qlo[5]), "+v"(qlo[6]), "+v"(qlo[7]),
                   "+v"(qhi[0]), "+v"(qhi[1]), "+v"(qhi[2]), "+v"(qhi[3]),
                   "+v"(qhi[4]), "+v"(qhi[5]), "+v"(qhi[6]), "+v"(qhi[7])
                 :: "memory");

    // ---- phase 3: interpolate ----
    float res[8];
    #pragma unroll
    for (int v = 0; v < 8; ++v) {
        unsigned int lox = (unsigned int)qlo[v];
        unsigned int loy = (unsigned int)(qlo[v] >> 32);
        unsigned int hix = (unsigned int)qhi[v];
        unsigned int hiy = (unsigned int)(qhi[v] >> 32);
        unsigned int a0 = xe[v] ? hix : lox;   // (z0,y0),(z1,y0) @ x0
        unsigned int a1 = xe[v] ? hiy : loy;   // (z0,y1),(z1,y1) @ x0

        float c000 = __uint_as_float(a0 << 16);
        float c100 = __uint_as_float(a0 & 0xFFFF0000u);
        float c010 = __uint_as_float(a1 << 16);
        float c110 = __uint_as_float(a1 & 0xFFFF0000u);
        float c001 = __uint_as_float(hix << 16);
        float c101 = __uint_as_float(hix & 0xFFFF0000u);
        float c011 = __uint_as_float(hiy << 16);
        float c111 = __uint_as_float(hiy & 0xFFFF0000u);

        float r00 = fmaf(fx[v], c001 - c000, c000);
        float r01 = fmaf(fx[v], c011 - c010, c010);
        float r10 = fmaf(fx[v], c101 - c100, c100);
        float r11 = fmaf(fx[v], c111 - c110, c110);
        float r0  = fmaf(fy[v], r01 - r00, r00);
        float r1  = fmaf(fy[v], r11 - r10, r10);
        res[v]    = fmaf(fz[v], r1 - r0, r0);
    }

    *(float4*)(out + base)     = make_float4(res[0], res[1], res[2], res[3]);
    *(float4*)(out + base + 4) = make_float4(res[4], res[5], res[6], res[7]);
}

// ---------------- fallback (proven R2 kernel) if ws too small ----------------
struct __align__(4) F2 { float a, b; };

__global__ __launch_bounds__(256) void warp_direct_kernel(
    const float* __restrict__ src,
    const float* __restrict__ flow,
    float* __restrict__ out)
{
    int b = blockIdx.x;
    int nb = (b & 7) * 600 + (b >> 3);
    int base = (nb * 256 + (int)threadIdx.x) * 4;

    int w = base % WW;
    int tmp = base / WW;
    int h = tmp % HH;
    int d = tmp / HH;

    const float4 f0  = *(const float4*)(flow + base);
    const float4 f1  = *(const float4*)(flow + DHW + base);
    const float4 f2v = *(const float4*)(flow + 2 * DHW + base);
    const float* f0p = (const float*)&f0;
    const float* f1p = (const float*)&f1;
    const float* f2p = (const float*)&f2v;

    const float SX = (float)WW / (float)(WW - 1);
    const float SY = (float)HH / (float)(HH - 1);
    const float SZ = (float)DD / (float)(DD - 1);

    float res[4];
    #pragma unroll
    for (int v = 0; v < 4; ++v) {
        float ux = fmaf((float)(w + v) + f2p[v], SX, -0.5f);
        float uy = fmaf((float)h + f1p[v],       SY, -0.5f);
        float uz = fmaf((float)d + f0p[v],       SZ, -0.5f);
        ux = fminf(fmaxf(ux, 0.0f), (float)(WW - 1));
        uy = fminf(fmaxf(uy, 0.0f), (float)(HH - 1));
        uz = fminf(fmaxf(uz, 0.0f), (float)(DD - 1));
        float x0f = floorf(ux), y0f = floorf(uy), z0f = floorf(uz);
        float fx = ux - x0f, fy = uy - y0f, fz = uz - z0f;
        int x0 = (int)x0f, y0 = (int)y0f, z0 = (int)z0f;
        int y1 = min(y0 + 1, HH - 1);
        int z1 = min(z0 + 1, DD - 1);
        int xb = min(x0, WW - 2);
        bool xe = (x0 == WW - 1);
        F2 q00 = *(const F2*)(src + ((size_t)z0 * HH + y0) * WW + xb);
        F2 q01 = *(const F2*)(src + ((size_t)z0 * HH + y1) * WW + xb);
        F2 q10 = *(const F2*)(src + ((size_t)z1 * HH + y0) * WW + xb);
        F2 q11 = *(const F2*)(src + ((size_t)z1 * HH + y1) * WW + xb);
        float c000 = xe ? q00.b : q00.a, c001 = q00.b;
        float c010 = xe ? q01.b : q01.a, c011 = q01.b;
        float c100 = xe ? q10.b : q10.a, c101 = q10.b;
        float c110 = xe ? q11.b : q11.a, c111 = q11.b;
        float r00 = fmaf(fx, c001 - c000, c000);
        float r01 = fmaf(fx, c011 - c010, c010);
        float r10 = fmaf(fx, c101 - c100, c100);
        float r11 = fmaf(fx, c111 - c110, c110);
        float r0  = fmaf(fy, r01 - r00, r00);
        float r1  = fmaf(fy, r11 - r10, r10);
        res[v]    = fmaf(fz, r1 - r0, r0);
    }
    *(float4*)(out + base) = make_float4(res[0], res[1], res[2], res[3]);
}

extern "C" void kernel_launch(void* const* d_in, const int* in_sizes, int n_in,
                              void* d_out, int out_size, void* d_ws, size_t ws_size,
                              hipStream_t stream) {
    const float* src  = (const float*)d_in[0];   // [1,1,D,H,W]
    const float* flow = (const float*)d_in[1];   // [1,3,D,H,W]
    // d_in[2] identity grid: unused (recomputed)
    float* out = (float*)d_out;

    if (ws_size >= WS_NEEDED) {
        unsigned int* tab = (unsigned int*)d_ws;
        pack_kernel<<<(ZP * YP * (WW / 4)) / 256, 256, 0, stream>>>(src, tab);
        warp_kernel<<<DHW / 8 / 256, 256, 0, stream>>>(tab, flow, out);  // 2400 = 8*300
    } else {
        warp_direct_kernel<<<DHW / 4 / 256, 256, 0, stream>>>(src, flow, out);
    }
}

// Round 8
// 176.658 us; speedup vs baseline: 1.0849x; 1.0800x over previous
//
#include <hip/hip_runtime.h>

// Spatial transformer: trilinear warp of src by flow, border padding.
// D=160, H=192, W=160.  u = (idx + flow) * S/(S-1) - 0.5, clamp, trilinear.
// grid input (identity meshgrid) recomputed from thread index.
//
// R2-R7 finding: scattered gathers cap at ~0.2 L1-miss-lines/cyc/CU
// (MSHR x latency), independent of per-wave MLP. Escape: gather from LDS.
// Single kernel: per 8x8x32 tile, stage 23x23x48 bf16 window (50.8 KB)
// straight from fp32 src (L2-resident slab) with unrolled coalesced loads,
// flow loads hoisted+pinned pre-barrier, 8 ds_read_u16/voxel, ~3%
// out-of-window fallback to direct scattered gathers.

#define DD 160
#define HH 192
#define WW 160
#define DHW (DD * HH * WW)

#define TZ 8
#define TY 8
#define TX 32
#define WIN_Z 23
#define WIN_Y 23
#define WIN_X 48
#define NTX 5
#define NTY 24
#define NTZ 20
#define NTILES (NTZ * NTY * NTX)            /* 2400 = 8*300 */
#define NCHUNK (WIN_Z * WIN_Y * (WIN_X / 8)) /* 529*6 = 3174 16B-chunks */
#define SROWY WIN_X                          /* +48 entries per y step */
#define SROWZ (WIN_Y * WIN_X)                /* +1104 entries per z step */

struct __align__(4) F2 { float a, b; };

__device__ __forceinline__ float bf2f(unsigned int s) {
    return __uint_as_float(s << 16);
}

__global__ __launch_bounds__(256) void warp_tile_kernel(
    const float* __restrict__ src,
    const float* __restrict__ flow,
    float* __restrict__ out)
{
    __shared__ unsigned short sbuf[WIN_Z * WIN_Y * WIN_X];  // 50,784 B

    // XCD swizzle: XCD k gets tiles [300k,300k+300) = contiguous z-slab;
    // its src slab (~2.7 MB incl halo) stays resident in that XCD's 4 MiB L2.
    int b = blockIdx.x;
    int nb = (b & 7) * 300 + (b >> 3);
    int tzt = nb / (NTY * NTX);
    int rem = nb - tzt * (NTY * NTX);
    int tyt = rem / NTX;
    int txt = rem - tyt * NTX;
    int bz = tzt * TZ, by = tyt * TY, bx = txt * TX;
    int zlo = bz - 7, ylo = by - 7, xlo = bx - 8;

    int tid = (int)threadIdx.x;

    // ---- voxel-group indices: 8 voxels/thread as 2 float4 groups ----
    int row0 = tid >> 3;                // 0..31
    int col  = tid & 7;
    int tz0 = row0 >> 3, ty0 = row0 & 7;
    int gz0 = bz + tz0, gy0 = by + ty0; // group 1 adds +4 to tz
    int gx  = bx + col * 4;
    int idx0 = (gz0 * HH + gy0) * WW + gx;
    int idx1 = idx0 + 4 * HH * WW;

    // ---- flow loads FIRST (in flight during staging; pinned pre-barrier) ----
    float4 f0a = *(const float4*)(flow + idx0);
    float4 f1a = *(const float4*)(flow + DHW + idx0);
    float4 f2a = *(const float4*)(flow + 2 * DHW + idx0);
    float4 f0b = *(const float4*)(flow + idx1);
    float4 f1b = *(const float4*)(flow + DHW + idx1);
    float4 f2b = *(const float4*)(flow + 2 * DHW + idx1);

    // ---- stage window: 3174 chunks of 8 entries (32B fp32 -> 16B bf16) ----
    #pragma unroll
    for (int k = 0; k < 13; ++k) {
        int c = tid + k * 256;
        if (c < NCHUNK) {
            int r = c / 6, i = c - r * 6;          // r: window row, i: x-chunk
            int wz = r / WIN_Y, wy = r - wz * WIN_Y;
            int gz = min(max(zlo + wz, 0), DD - 1);
            int gy = min(max(ylo + wy, 0), HH - 1);
            const float* rowp = src + (gz * HH + gy) * WW;
            int gx0 = xlo + i * 8;                 // -8, [0,152], or 160
            float4 a, bb;
            if ((unsigned)gx0 <= (unsigned)(WW - 8)) {
                a  = *(const float4*)(rowp + gx0);
                bb = *(const float4*)(rowp + gx0 + 4);
            } else {                               // fully-clamped chunk
                float v = rowp[gx0 < 0 ? 0 : WW - 1];
                a = make_float4(v, v, v, v); bb = a;
            }
            // bf16 round-half-up pack (2 per u32)
            unsigned a0 = __float_as_uint(a.x) + 0x8000u, a1 = __float_as_uint(a.y) + 0x8000u;
            unsigned a2 = __float_as_uint(a.z) + 0x8000u, a3 = __float_as_uint(a.w) + 0x8000u;
            unsigned b0 = __float_as_uint(bb.x) + 0x8000u, b1 = __float_as_uint(bb.y) + 0x8000u;
            unsigned b2 = __float_as_uint(bb.z) + 0x8000u, b3 = __float_as_uint(bb.w) + 0x8000u;
            uint4 pk;
            pk.x = (a1 & 0xFFFF0000u) | (a0 >> 16);
            pk.y = (a3 & 0xFFFF0000u) | (a2 >> 16);
            pk.z = (b1 & 0xFFFF0000u) | (b0 >> 16);
            pk.w = (b3 & 0xFFFF0000u) | (b2 >> 16);
            *(uint4*)&sbuf[r * WIN_X + i * 8] = pk;
        }
    }

    // Pin flow values into VGPRs before the barrier: their waitcnt merges
    // with the pre-barrier drain -> post-barrier compute has no global
    // latency exposure (R6's killer).
    asm volatile("" :
        "+v"(f0a.x), "+v"(f0a.y), "+v"(f0a.z), "+v"(f0a.w),
        "+v"(f1a.x), "+v"(f1a.y), "+v"(f1a.z), "+v"(f1a.w),
        "+v"(f2a.x), "+v"(f2a.y), "+v"(f2a.z), "+v"(f2a.w),
        "+v"(f0b.x), "+v"(f0b.y), "+v"(f0b.z), "+v"(f0b.w),
        "+v"(f1b.x), "+v"(f1b.y), "+v"(f1b.z), "+v"(f1b.w),
        "+v"(f2b.x), "+v"(f2b.y), "+v"(f2b.z), "+v"(f2b.w));
    __syncthreads();

    const float SX = (float)WW / (float)(WW - 1);
    const float SY = (float)HH / (float)(HH - 1);
    const float SZ = (float)DD / (float)(DD - 1);

    // ---- compute: 2 groups x 4 voxels ----
    #pragma unroll
    for (int g2 = 0; g2 < 2; ++g2) {
        int gz = gz0 + g2 * 4, gy = gy0;
        int idx = g2 ? idx1 : idx0;
        const float4 fz4 = g2 ? f0b : f0a;
        const float4 fy4 = g2 ? f1b : f1a;
        const float4 fx4 = g2 ? f2b : f2a;
        const float* pzf = (const float*)&fz4;
        const float* pyf = (const float*)&fy4;
        const float* pxf = (const float*)&fx4;

        float res[4];
        #pragma unroll
        for (int v = 0; v < 4; ++v) {
            float ux = fmaf((float)(gx + v) + pxf[v], SX, -0.5f);
            float uy = fmaf((float)gy + pyf[v],       SY, -0.5f);
            float uz = fmaf((float)gz + pzf[v],       SZ, -0.5f);
            ux = fminf(fmaxf(ux, 0.0f), (float)(WW - 1));
            uy = fminf(fmaxf(uy, 0.0f), (float)(HH - 1));
            uz = fminf(fmaxf(uz, 0.0f), (float)(DD - 1));
            float x0f = floorf(ux), y0f = floorf(uy), z0f = floorf(uz);
            float fx = ux - x0f, fy = uy - y0f, fz = uz - z0f;
            int x0 = (int)x0f, y0 = (int)y0f, z0 = (int)z0f;
            int lx0 = x0 - xlo, ly0 = y0 - ylo, lz0 = z0 - zlo;
            // window replication rows make explicit +1 clamps unnecessary
            bool in = ((unsigned)lz0 <= (unsigned)(WIN_Z - 2)) &
                      ((unsigned)ly0 <= (unsigned)(WIN_Y - 2)) &
                      ((unsigned)lx0 <= (unsigned)(WIN_X - 2));

            float c000, c001, c010, c011, c100, c101, c110, c111;
            if (in) {
                int e = (lz0 * WIN_Y + ly0) * WIN_X + lx0;  // one addr, imm offs
                c000 = bf2f(sbuf[e]);              c001 = bf2f(sbuf[e + 1]);
                c010 = bf2f(sbuf[e + SROWY]);      c011 = bf2f(sbuf[e + SROWY + 1]);
                c100 = bf2f(sbuf[e + SROWZ]);      c101 = bf2f(sbuf[e + SROWZ + 1]);
                c110 = bf2f(sbuf[e + SROWZ + SROWY]); c111 = bf2f(sbuf[e + SROWZ + SROWY + 1]);
            } else {
                // rare (~3%): direct scattered gathers (proven R2 path)
                int y1 = min(y0 + 1, HH - 1);
                int z1 = min(z0 + 1, DD - 1);
                int xb = min(x0, WW - 2);
                bool xe = (x0 == WW - 1);
                F2 q00 = *(const F2*)(src + ((size_t)z0 * HH + y0) * WW + xb);
                F2 q01 = *(const F2*)(src + ((size_t)z0 * HH + y1) * WW + xb);
                F2 q10 = *(const F2*)(src + ((size_t)z1 * HH + y0) * WW + xb);
                F2 q11 = *(const F2*)(src + ((size_t)z1 * HH + y1) * WW + xb);
                c000 = xe ? q00.b : q00.a; c001 = q00.b;
                c010 = xe ? q01.b : q01.a; c011 = q01.b;
                c100 = xe ? q10.b : q10.a; c101 = q10.b;
                c110 = xe ? q11.b : q11.a; c111 = q11.b;
            }
            float r00 = fmaf(fx, c001 - c000, c000);
            float r01 = fmaf(fx, c011 - c010, c010);
            float r10 = fmaf(fx, c101 - c100, c100);
            float r11 = fmaf(fx, c111 - c110, c110);
            float r0  = fmaf(fy, r01 - r00, r00);
            float r1  = fmaf(fy, r11 - r10, r10);
            res[v]    = fmaf(fz, r1 - r0, r0);
        }
        *(float4*)(out + idx) = make_float4(res[0], res[1], res[2], res[3]);
    }
}

extern "C" void kernel_launch(void* const* d_in, const int* in_sizes, int n_in,
                              void* d_out, int out_size, void* d_ws, size_t ws_size,
                              hipStream_t stream) {
    const float* src  = (const float*)d_in[0];   // [1,1,D,H,W]
    const float* flow = (const float*)d_in[1];   // [1,3,D,H,W]
    // d_in[2] identity grid: unused (recomputed); d_ws unused
    float* out = (float*)d_out;

    warp_tile_kernel<<<NTILES, 256, 0, stream>>>(src, flow, out);
}